// Round 4
// baseline (18388.429 us; speedup 1.0000x reference)
//
#include <hip/hip_runtime.h>
#include <hip/hip_cooperative_groups.h>
#include <stdint.h>

namespace cg = cooperative_groups;

// Problem constants (B=256, D=1024, T=128)
#define B_ROWS 256
#define DDIM   1024
#define TSTEPS 128
#define THREE_D 3072
#define OSTRIDE (TSTEPS * DDIM)   // out row stride (per batch row)

typedef short bf16x8 __attribute__((ext_vector_type(8)));
typedef float f32x4  __attribute__((ext_vector_type(4)));
typedef unsigned short u16x8 __attribute__((ext_vector_type(8)));

static __device__ __forceinline__ unsigned short f2bf(float f) {
    union { float f; uint32_t u; } v; v.f = f;
    uint32_t u = v.u;
    uint32_t r = u + 0x7FFFu + ((u >> 16) & 1u);   // round-to-nearest-even
    return (unsigned short)(r >> 16);
}
static __device__ __forceinline__ float bf2f(unsigned short h) {
    union { uint32_t u; float f; } v; v.u = ((uint32_t)h) << 16; return v.f;
}

// ---------------------------------------------------------------------------
// Pack item (one 16-byte fragment slot) for the folded matrix
// M1 = [Wz+Uz | Wr+Ur | Wh | Uh] and the step-0 matrix M0 = [Uz | Ur | 0 | Uh],
// both split into hi+lo bf16. Layout (validated rounds 2-3):
//   pack[ntile(0..255)][ktile(0..31)][lane(0..63)][j(0..7)]
//   col = ntile*16 + (lane&15),  k = ktile*32 + (lane>>4)*8 + j
// ---------------------------------------------------------------------------
static __device__ __forceinline__ void pack_item(
    int t, const float* __restrict__ W, const float* __restrict__ U,
    unsigned short* __restrict__ p1h, unsigned short* __restrict__ p1l,
    unsigned short* __restrict__ p0h, unsigned short* __restrict__ p0l)
{
    int lane  = t & 63;
    int ktile = (t >> 6) & 31;
    int ntile = t >> 11;                       // 0..255
    int col = ntile * 16 + (lane & 15);
    int q = col >> 10;
    int d = col & 1023;
    int k8 = ktile * 32 + ((lane >> 4) << 3);

    u16x8 o1h, o1l, o0h, o0l;
    #pragma unroll
    for (int j = 0; j < 8; ++j) {
        int k = k8 + j;
        const float* wr = W + (size_t)k * THREE_D;
        const float* ur = U + (size_t)k * THREE_D;
        float v1, v0;
        if (q == 0)      { float u = ur[d];        v1 = wr[d] + u;        v0 = u; }
        else if (q == 1) { float u = ur[1024 + d]; v1 = wr[1024 + d] + u; v0 = u; }
        else if (q == 2) { v1 = wr[2048 + d]; v0 = 0.0f; }
        else             { float u = ur[2048 + d]; v1 = u; v0 = u; }
        unsigned short h1 = f2bf(v1);
        o1h[j] = h1; o1l[j] = f2bf(v1 - bf2f(h1));
        unsigned short h0 = f2bf(v0);
        o0h[j] = h0; o0l[j] = f2bf(v0 - bf2f(h0));
    }
    size_t base = ((size_t)(ntile * 32 + ktile) * 64 + lane) * 8;
    *(u16x8*)(p1h + base) = o1h;
    *(u16x8*)(p1l + base) = o1l;
    *(u16x8*)(p0h + base) = o0h;
    *(u16x8*)(p0l + base) = o0l;
}

// ---------------------------------------------------------------------------
// Persistent kernel: packs weights, then runs all 128 GRU steps with
// grid.sync() between steps.
// Grid 256 blocks (1/CU) x 1024 threads (16 waves = 4 waves/SIMD).
// Block (dt = blk&63, rt = blk>>6) owns C-tile rows rt*64..+63, dims dt*16..+15
// (all 4 gate quarters). Wave roles: q = w&3 (gate), kh = (w>>2)&1 (K half,
// 512 k), mh = w>>3 (m half, 2 of 4 row-tiles). Per wave per step:
// 16 kt x 2 m x 3 MFMA = 96 MFMA, two 4-VGPR acc chains (no spill at the
// 128-VGPR/wave cap). K-half partials combined via LDS atomicAdd (ds_add_f32,
// 2-way, pad-17 rows = conflict-free).
// Each thread owns one (row,dim) element: f32 h carried in a REGISTER across
// all steps; epilogue writes out[t], hi/lo bf16 state, then grid.sync.
// ---------------------------------------------------------------------------
__global__ __launch_bounds__(1024) void gru_all(
    const float* __restrict__ x, const float* __restrict__ W,
    const float* __restrict__ U, const float* __restrict__ bias,
    float* __restrict__ out,
    unsigned short* __restrict__ p1h, unsigned short* __restrict__ p1l,
    unsigned short* __restrict__ p0h, unsigned short* __restrict__ p0l,
    unsigned short* __restrict__ h0h, unsigned short* __restrict__ h0l,
    unsigned short* __restrict__ h1h, unsigned short* __restrict__ h1l)
{
    cg::grid_group grid = cg::this_grid();
    __shared__ float pbuf[4][64][17];   // [gate][row][dim], +1 pad -> 17.4 KB

    const int tid = threadIdx.x;
    const int blk = blockIdx.x;
    const int dt  = blk & 63;
    const int rt  = blk >> 6;

    // ---- phase 0: pack weights (2 items each of 524288) + init own element
    {
        int gt = blk * 1024 + tid;               // 0..262143
        pack_item(gt,          W, U, p1h, p1l, p0h, p0l);
        pack_item(gt + 262144, W, U, p1h, p1l, p0h, p0l);
    }

    const int row  = tid >> 4;          // 0..63
    const int col  = tid & 15;          // 0..15
    const int grow = rt * 64 + row;
    const int d    = dt * 16 + col;
    const size_t hoff = (size_t)grow * DDIM + d;

    float hp = x[hoff];                 // f32 state, register-resident
    {
        unsigned short hi = f2bf(hp);
        h0h[hoff] = hi;
        h0l[hoff] = f2bf(hp - bf2f(hi));
    }
    const float bz  = bias[d];
    const float br  = bias[1024 + d];
    const float bhb = bias[2048 + d];
    float* outp = out + (size_t)grow * OSTRIDE + d;

    {   // zero partial buffer once (re-zeroed at end of each step)
        float* pf = &pbuf[0][0][0];
        for (int i = tid; i < 4 * 64 * 17; i += 1024) pf[i] = 0.0f;
    }

    // ---- MFMA roles
    const int lane = tid & 63;
    const int w    = tid >> 6;
    const int q    = w & 3;             // gate quarter
    const int kh   = (w >> 2) & 1;      // K half (16 ktiles = 512 k)
    const int mh   = w >> 3;            // m half (2 row-tiles of 16)
    const int llow = lane & 15;
    const int lhi  = lane >> 4;

    const int ntile = q * 64 + dt;
    const size_t bbase = ((size_t)ntile * 32 + (size_t)kh * 16) * 512 + (size_t)lane * 8;
    const size_t abase = (size_t)(rt * 64 + mh * 32 + llow) * DDIM + kh * 512 + lhi * 8;

    // LDS target rows for the two acc chains
    const int prow0 = (mh * 2) * 16 + lhi * 4;
    const int prow1 = (mh * 2 + 1) * 16 + lhi * 4;

    __threadfence();
    grid.sync();

    // ---- 128 GRU steps
    for (int t = 0; t < TSTEPS; ++t) {
        const unsigned short* bhp = ((t == 0) ? p0h : p1h) + bbase;
        const unsigned short* blp = ((t == 0) ? p0l : p1l) + bbase;
        const unsigned short* ahp = ((t & 1) ? h1h : h0h) + abase;
        const unsigned short* alp = ((t & 1) ? h1l : h0l) + abase;
        unsigned short* hoh = (t & 1) ? h0h : h1h;
        unsigned short* hol = (t & 1) ? h0l : h1l;

        f32x4 acc0 = {0.f, 0.f, 0.f, 0.f};
        f32x4 acc1 = {0.f, 0.f, 0.f, 0.f};

        #pragma unroll 2
        for (int kt = 0; kt < 16; ++kt) {
            bf16x8 bh  = *(const bf16x8*)(bhp + kt * 512);
            bf16x8 bl  = *(const bf16x8*)(blp + kt * 512);
            bf16x8 a0h = *(const bf16x8*)(ahp + kt * 32);
            bf16x8 a0l = *(const bf16x8*)(alp + kt * 32);
            bf16x8 a1h = *(const bf16x8*)(ahp + 16 * DDIM + kt * 32);
            bf16x8 a1l = *(const bf16x8*)(alp + 16 * DDIM + kt * 32);
            acc0 = __builtin_amdgcn_mfma_f32_16x16x32_bf16(a0h, bh, acc0, 0, 0, 0);
            acc0 = __builtin_amdgcn_mfma_f32_16x16x32_bf16(a0l, bh, acc0, 0, 0, 0);
            acc0 = __builtin_amdgcn_mfma_f32_16x16x32_bf16(a0h, bl, acc0, 0, 0, 0);
            acc1 = __builtin_amdgcn_mfma_f32_16x16x32_bf16(a1h, bh, acc1, 0, 0, 0);
            acc1 = __builtin_amdgcn_mfma_f32_16x16x32_bf16(a1l, bh, acc1, 0, 0, 0);
            acc1 = __builtin_amdgcn_mfma_f32_16x16x32_bf16(a1h, bl, acc1, 0, 0, 0);
        }

        // combine K-half partials (C/D layout: col=lane&15, row=(lane>>4)*4+reg)
        #pragma unroll
        for (int r = 0; r < 4; ++r) {
            atomicAdd(&pbuf[q][prow0 + r][llow], acc0[r]);
            atomicAdd(&pbuf[q][prow1 + r][llow], acc1[r]);
        }
        __syncthreads();

        // gate epilogue: one element per thread
        float gz = pbuf[0][row][col] + bz;
        float gr = pbuf[1][row][col] + br;
        float gx = pbuf[2][row][col] + bhb;
        float gu = pbuf[3][row][col];
        float z  = 1.0f / (1.0f + __expf(-gz));
        float r_ = 1.0f / (1.0f + __expf(-gr));
        float hh = tanhf(gx + r_ * gu);
        float hn = z * hp + (1.0f - z) * hh;
        hp = hn;
        outp[t * DDIM] = hn;
        unsigned short hi = f2bf(hn);
        hoh[hoff] = hi;
        hol[hoff] = f2bf(hn - bf2f(hi));
        __syncthreads();                 // all pbuf reads done

        {   // re-zero partials for next step
            float* pf = &pbuf[0][0][0];
            for (int i = tid; i < 4 * 64 * 17; i += 1024) pf[i] = 0.0f;
        }
        __threadfence();
        grid.sync();                     // publish h(t) to all blocks
    }
}

extern "C" void kernel_launch(void* const* d_in, const int* in_sizes, int n_in,
                              void* d_out, int out_size, void* d_ws, size_t ws_size,
                              hipStream_t stream) {
    const float* x = (const float*)d_in[0];
    const float* W = (const float*)d_in[1];
    const float* U = (const float*)d_in[2];
    const float* b = (const float*)d_in[3];
    float* out = (float*)d_out;

    char* ws = (char*)d_ws;
    // ws layout (34 MB used; ws is 512 MB per harness fill evidence):
    unsigned short* p1h = (unsigned short*)ws;                      // 8 MB
    unsigned short* p1l = (unsigned short*)(ws + (8u << 20));       // 8 MB
    unsigned short* p0h = (unsigned short*)(ws + (16u << 20));      // 8 MB
    unsigned short* p0l = (unsigned short*)(ws + (24u << 20));      // 8 MB
    char* hbase = ws + (32u << 20);
    unsigned short* h0h = (unsigned short*)hbase;                   // 0.5 MB
    unsigned short* h0l = (unsigned short*)(hbase + (512u << 10));
    unsigned short* h1h = (unsigned short*)(hbase + (1024u << 10));
    unsigned short* h1l = (unsigned short*)(hbase + (1536u << 10));

    void* args[] = {
        (void*)&x, (void*)&W, (void*)&U, (void*)&b, (void*)&out,
        (void*)&p1h, (void*)&p1l, (void*)&p0h, (void*)&p0l,
        (void*)&h0h, (void*)&h0l, (void*)&h1h, (void*)&h1l
    };
    hipLaunchCooperativeKernel((const void*)gru_all, dim3(256), dim3(1024),
                               args, 0, stream);
}

// Round 5
// 4779.129 us; speedup vs baseline: 3.8477x; 3.8477x over previous
//
#include <hip/hip_runtime.h>
#include <stdint.h>

// Problem constants (B=256, D=1024, T=128)
#define B_ROWS 256
#define DDIM   1024
#define TSTEPS 128
#define THREE_D 3072
#define OSTRIDE (TSTEPS * DDIM)   // out row stride (per batch row)

typedef short bf16x8 __attribute__((ext_vector_type(8)));
typedef float f32x4  __attribute__((ext_vector_type(4)));
typedef unsigned short u16x8 __attribute__((ext_vector_type(8)));

static __device__ __forceinline__ unsigned short f2bf(float f) {
    union { float f; uint32_t u; } v; v.f = f;
    uint32_t u = v.u;
    uint32_t r = u + 0x7FFFu + ((u >> 16) & 1u);   // round-to-nearest-even
    return (unsigned short)(r >> 16);
}
static __device__ __forceinline__ float bf2f(unsigned short h) {
    union { uint32_t u; float f; } v; v.u = ((uint32_t)h) << 16; return v.f;
}

// ---------------------------------------------------------------------------
// Pack folded weights (steps>=1) into hi+lo bf16 pairs in MFMA B-fragment
// order. M1 = [Wz+Uz | Wr+Ur | Wh | Uh]  (f32 fold, then hi/lo split).
// Layout (validated rounds 2-3): pack[ntile][ktile][lane][j]
//   col = ntile*16 + (lane&15),  k = ktile*32 + (lane>>4)*8 + j
// ---------------------------------------------------------------------------
__global__ __launch_bounds__(256) void pack_kernel(
    const float* __restrict__ W, const float* __restrict__ U,
    unsigned short* __restrict__ phi, unsigned short* __restrict__ plo)
{
    int t = blockIdx.x * 256 + threadIdx.x;   // 524288 threads
    int lane  = t & 63;
    int ktile = (t >> 6) & 31;
    int ntile = t >> 11;                       // 0..255
    int col = ntile * 16 + (lane & 15);
    int q = col >> 10;                         // wave-uniform
    int d = col & 1023;
    int k8 = ktile * 32 + ((lane >> 4) << 3);

    u16x8 ohi, olo;
    #pragma unroll
    for (int j = 0; j < 8; ++j) {
        int k = k8 + j;
        const float* wr = W + (size_t)k * THREE_D;
        const float* ur = U + (size_t)k * THREE_D;
        float v;
        if (q == 0)      v = wr[d] + ur[d];
        else if (q == 1) v = wr[1024 + d] + ur[1024 + d];
        else if (q == 2) v = wr[2048 + d];
        else             v = ur[2048 + d];
        unsigned short hi = f2bf(v);
        ohi[j] = hi;
        olo[j] = f2bf(v - bf2f(hi));
    }
    size_t base = ((size_t)(ntile * 32 + ktile) * 64 + lane) * 8;
    *(u16x8*)(phi + base) = ohi;
    *(u16x8*)(plo + base) = olo;
}

// Step-0 packed matrix: [Uz | Ur | 0 | Uh]  (hi+lo). Same layout.
__global__ __launch_bounds__(256) void pack0_kernel(
    const float* __restrict__ U,
    unsigned short* __restrict__ phi, unsigned short* __restrict__ plo)
{
    int t = blockIdx.x * 256 + threadIdx.x;
    int lane  = t & 63;
    int ktile = (t >> 6) & 31;
    int ntile = t >> 11;
    int col = ntile * 16 + (lane & 15);
    int q = col >> 10;
    int d = col & 1023;
    int k8 = ktile * 32 + ((lane >> 4) << 3);

    u16x8 ohi, olo;
    #pragma unroll
    for (int j = 0; j < 8; ++j) {
        int k = k8 + j;
        const float* ur = U + (size_t)k * THREE_D;
        float v;
        if (q == 0)      v = ur[d];
        else if (q == 1) v = ur[1024 + d];
        else if (q == 2) v = 0.0f;
        else             v = ur[2048 + d];
        unsigned short hi = f2bf(v);
        ohi[j] = hi;
        olo[j] = f2bf(v - bf2f(hi));
    }
    size_t base = ((size_t)(ntile * 32 + ktile) * 64 + lane) * 8;
    *(u16x8*)(phi + base) = ohi;
    *(u16x8*)(plo + base) = olo;
}

// Quantize x (f32 initial state) into hi+lo bf16 state buffers.
__global__ __launch_bounds__(256) void init_x(
    const float* __restrict__ x,
    unsigned short* __restrict__ xh, unsigned short* __restrict__ xl)
{
    int i = blockIdx.x * 256 + threadIdx.x;
    if (i < B_ROWS * DDIM) {
        float v = x[i];
        unsigned short h = f2bf(v);
        xh[i] = h;
        xl[i] = f2bf(v - bf2f(h));
    }
}

// ---------------------------------------------------------------------------
// One GRU step, fused GEMM (split-bf16, 3 cross terms) + gates.
// Grid 256 blocks (1/CU): dt = blk&63 (16 dims), rt = blk>>6 (64 rows);
// same-dt blocks land on the same XCD (%8) -> packed B stays L2-resident.
// Block = 512 threads = 8 waves = 2 waves/SIMD (TLP; round 2 had 1/SIMD and
// was latency-bound at ~32 us/step). __launch_bounds__(512,2): 256-VGPR cap.
// Wave roles: q = w&3 (gate quarter), mh = w>>2 (m half). Each wave: 2 m-tiles
// (32 rows) x 1 ntile, full K=1024: 32 kt x 2 m x 3 MFMA = 192 MFMA, two
// 4-VGPR acc chains. K-loop fully unrolled with distance-1 prefetch of all 6
// fragments so kt+1 loads overlap kt's MFMAs. Plain LDS stores (waves own
// disjoint rows), single barrier, 2-elem/thread gate epilogue.
// f32 prev state read from hprev (x for t=0, out[t-1] otherwise).
// ---------------------------------------------------------------------------
__global__ __launch_bounds__(512, 2) void gru_step(
    const unsigned short* __restrict__ phi,
    const unsigned short* __restrict__ plo,
    const unsigned short* __restrict__ hbh_in,
    const unsigned short* __restrict__ hbl_in,
    const float* __restrict__ bias,
    const float* __restrict__ hprev, int hstride,
    float* __restrict__ out_t,
    unsigned short* __restrict__ hbh_out,
    unsigned short* __restrict__ hbl_out)
{
    __shared__ float gbuf[4][64][17];   // [gate][row][dim], +1 pad -> 17.4 KB
    const int tid  = threadIdx.x;
    const int w    = tid >> 6;
    const int lane = tid & 63;
    const int q    = w & 3;             // gate quarter
    const int mh   = w >> 2;            // m half (rows mh*32 .. +31)
    const int dt   = blockIdx.x & 63;   // dim tile (16 dims)
    const int rt   = blockIdx.x >> 6;   // row tile (64 rows)
    const int llow = lane & 15;
    const int lhi  = lane >> 4;

    f32x4 acc0 = {0.f, 0.f, 0.f, 0.f};
    f32x4 acc1 = {0.f, 0.f, 0.f, 0.f};

    const int ntile = q * 64 + dt;
    const unsigned short* bhp = phi + (size_t)ntile * 16384 + (size_t)lane * 8;
    const unsigned short* blp = plo + (size_t)ntile * 16384 + (size_t)lane * 8;
    const size_t arow = (size_t)(rt * 64 + mh * 32 + llow) * DDIM + lhi * 8;
    const unsigned short* ahp = hbh_in + arow;   // tile m: +m*16*DDIM, kt: +kt*32
    const unsigned short* alp = hbl_in + arow;

    // --- software-pipelined K-loop (prefetch distance 1) ---
    bf16x8 cbh  = *(const bf16x8*)(bhp);
    bf16x8 cbl  = *(const bf16x8*)(blp);
    bf16x8 ca0h = *(const bf16x8*)(ahp);
    bf16x8 ca0l = *(const bf16x8*)(alp);
    bf16x8 ca1h = *(const bf16x8*)(ahp + 16 * DDIM);
    bf16x8 ca1l = *(const bf16x8*)(alp + 16 * DDIM);

    #pragma unroll
    for (int kt = 0; kt < 32; ++kt) {
        bf16x8 nbh, nbl, na0h, na0l, na1h, na1l;
        if (kt < 31) {
            const int ko = (kt + 1) * 512;
            const int ka = (kt + 1) * 32;
            nbh  = *(const bf16x8*)(bhp + ko);
            nbl  = *(const bf16x8*)(blp + ko);
            na0h = *(const bf16x8*)(ahp + ka);
            na0l = *(const bf16x8*)(alp + ka);
            na1h = *(const bf16x8*)(ahp + 16 * DDIM + ka);
            na1l = *(const bf16x8*)(alp + 16 * DDIM + ka);
        }
        acc0 = __builtin_amdgcn_mfma_f32_16x16x32_bf16(ca0h, cbh, acc0, 0, 0, 0);
        acc0 = __builtin_amdgcn_mfma_f32_16x16x32_bf16(ca0l, cbh, acc0, 0, 0, 0);
        acc0 = __builtin_amdgcn_mfma_f32_16x16x32_bf16(ca0h, cbl, acc0, 0, 0, 0);
        acc1 = __builtin_amdgcn_mfma_f32_16x16x32_bf16(ca1h, cbh, acc1, 0, 0, 0);
        acc1 = __builtin_amdgcn_mfma_f32_16x16x32_bf16(ca1l, cbh, acc1, 0, 0, 0);
        acc1 = __builtin_amdgcn_mfma_f32_16x16x32_bf16(ca1h, cbl, acc1, 0, 0, 0);
        cbh = nbh; cbl = nbl;
        ca0h = na0h; ca0l = na0l; ca1h = na1h; ca1l = na1l;
    }

    // C/D layout: col = lane&15, row = (lane>>4)*4 + reg  [measured m89]
    const int gr0 = mh * 32 + lhi * 4;
    #pragma unroll
    for (int r = 0; r < 4; ++r) {
        gbuf[q][gr0 + r][llow]      = acc0[r];
        gbuf[q][gr0 + 16 + r][llow] = acc1[r];
    }
    __syncthreads();

    // Gate epilogue: 64x16 = 1024 elements over 512 threads (2 each)
    #pragma unroll
    for (int i = 0; i < 2; ++i) {
        int e = tid + i * 512;
        int row = e >> 4, col = e & 15;
        int d = dt * 16 + col;
        int grow = rt * 64 + row;
        float gz = gbuf[0][row][col] + bias[d];
        float gr = gbuf[1][row][col] + bias[1024 + d];
        float gx = gbuf[2][row][col] + bias[2048 + d];
        float gu = gbuf[3][row][col];
        float z  = 1.0f / (1.0f + __expf(-gz));
        float r_ = 1.0f / (1.0f + __expf(-gr));
        float hh = tanhf(gx + r_ * gu);
        float hp = hprev[(size_t)grow * hstride + d];   // exact f32 prev state
        float hn = z * hp + (1.0f - z) * hh;
        out_t[(size_t)grow * OSTRIDE + d] = hn;
        unsigned short hi = f2bf(hn);
        size_t hoff = (size_t)grow * DDIM + d;
        hbh_out[hoff] = hi;
        hbl_out[hoff] = f2bf(hn - bf2f(hi));
    }
}

// ---------------------------------------------------------------------------
// Fallback step 0 in exact f32 (used only if workspace < 34 MB).
// ---------------------------------------------------------------------------
__global__ __launch_bounds__(256) void gru_step0(
    const float* __restrict__ x, const float* __restrict__ U,
    const float* __restrict__ bias,
    float* __restrict__ out,
    unsigned short* __restrict__ hbh, unsigned short* __restrict__ hbl)
{
    __shared__ float xt[16][64];
    const int tid = threadIdx.x;
    const int c   = tid & 63;
    const int rg  = tid >> 6;
    const int dt  = blockIdx.x & 15;
    const int rt  = blockIdx.x >> 4;

    float acc[4][3];
    #pragma unroll
    for (int rr = 0; rr < 4; ++rr) { acc[rr][0] = 0.f; acc[rr][1] = 0.f; acc[rr][2] = 0.f; }

    for (int kc = 0; kc < 16; ++kc) {
        #pragma unroll
        for (int i = 0; i < 4; ++i) {
            int e = i * 256 + tid;
            int row = e >> 6, kk = e & 63;
            xt[row][kk] = x[(size_t)(rt * 16 + row) * DDIM + kc * 64 + kk];
        }
        __syncthreads();
        #pragma unroll 4
        for (int kk = 0; kk < 64; ++kk) {
            int k = kc * 64 + kk;
            const float* up = U + (size_t)k * THREE_D + dt * 64 + c;
            float uz = up[0], ur = up[1024], uh = up[2048];
            #pragma unroll
            for (int rr = 0; rr < 4; ++rr) {
                float xv = xt[rg * 4 + rr][kk];
                acc[rr][0] += xv * uz;
                acc[rr][1] += xv * ur;
                acc[rr][2] += xv * uh;
            }
        }
        __syncthreads();
    }

    int d = dt * 64 + c;
    #pragma unroll
    for (int rr = 0; rr < 4; ++rr) {
        int row = rt * 16 + rg * 4 + rr;
        float z  = 1.0f / (1.0f + __expf(-(acc[rr][0] + bias[d])));
        float r  = 1.0f / (1.0f + __expf(-(acc[rr][1] + bias[1024 + d])));
        float hh = tanhf(bias[2048 + d] + r * acc[rr][2]);
        float hp = x[(size_t)row * DDIM + d];
        float hn = z * hp + (1.0f - z) * hh;
        out[(size_t)row * OSTRIDE + d] = hn;
        unsigned short hi = f2bf(hn);
        size_t off = (size_t)row * DDIM + d;
        hbh[off] = hi;
        hbl[off] = f2bf(hn - bf2f(hi));
    }
}

extern "C" void kernel_launch(void* const* d_in, const int* in_sizes, int n_in,
                              void* d_out, int out_size, void* d_ws, size_t ws_size,
                              hipStream_t stream) {
    const float* x = (const float*)d_in[0];
    const float* W = (const float*)d_in[1];
    const float* U = (const float*)d_in[2];
    const float* b = (const float*)d_in[3];
    float* out = (float*)d_out;

    char* ws = (char*)d_ws;
    // ws layout: p1 (16 MB) + h buffers (2 MB) + p0 (16 MB) -> 34 MB
    unsigned short* p1h = (unsigned short*)ws;                      // 8 MB
    unsigned short* p1l = (unsigned short*)(ws + (8u << 20));       // 8 MB
    char* hbase = ws + (16u << 20);
    unsigned short* hbh[2] = { (unsigned short*)hbase,
                               (unsigned short*)(hbase + (512u << 10)) };
    unsigned short* hbl[2] = { (unsigned short*)(hbase + (1024u << 10)),
                               (unsigned short*)(hbase + (1536u << 10)) };
    unsigned short* p0h = (unsigned short*)(ws + (18u << 20));      // 8 MB (optional)
    unsigned short* p0l = (unsigned short*)(ws + (26u << 20));      // 8 MB (optional)
    const bool mfma_step0 = (ws_size >= (34ull << 20));             // constant per harness

    hipLaunchKernelGGL(pack_kernel, dim3(2048), dim3(256), 0, stream, W, U, p1h, p1l);

    if (mfma_step0) {
        hipLaunchKernelGGL(pack0_kernel, dim3(2048), dim3(256), 0, stream, U, p0h, p0l);
        // stage quantized x in the [1] buffers (step 0 writes [0], step 1 reads [0])
        hipLaunchKernelGGL(init_x, dim3(1024), dim3(256), 0, stream, x, hbh[1], hbl[1]);
        hipLaunchKernelGGL(gru_step, dim3(256), dim3(512), 0, stream,
                           p0h, p0l, hbh[1], hbl[1], b,
                           x, DDIM,                 // prev f32 state = x
                           out,                     // t = 0 slice
                           hbh[0], hbl[0]);
    } else {
        hipLaunchKernelGGL(gru_step0, dim3(256), dim3(256), 0, stream, x, U, b,
                           out, hbh[0], hbl[0]);
    }

    for (int t = 1; t < TSTEPS; ++t) {
        int src = (t - 1) & 1;
        int dst = t & 1;
        hipLaunchKernelGGL(gru_step, dim3(256), dim3(512), 0, stream,
                           p1h, p1l, hbh[src], hbl[src], b,
                           out + (size_t)(t - 1) * DDIM, OSTRIDE,
                           out + (size_t)t * DDIM,
                           hbh[dst], hbl[dst]);
    }
}